// Round 11
// baseline (392.915 us; speedup 1.0000x reference)
//
#include <hip/hip_runtime.h>
#include <hip/hip_bf16.h>
#include <cstdint>
#include <cstddef>

// Problem constants
#define BB   512
#define NN   100
#define HH   768
#define II   1536
#define MM   (BB*NN)          // 51200 rows

typedef __bf16 bf16;
typedef __bf16 bf16x8 __attribute__((ext_vector_type(8)));
typedef float  f32x4  __attribute__((ext_vector_type(4)));
typedef float  f32x4v __attribute__((ext_vector_type(4)));

// async global -> LDS, 16B per lane (wave-uniform LDS base + lane*16)
__device__ __forceinline__ void gld_lds16(const void* g, void* l) {
    __builtin_amdgcn_global_load_lds(
        (const __attribute__((address_space(1))) void*)g,
        (__attribute__((address_space(3))) void*)l, 16, 0, 0);
}

// 16-lane-group sum via DPP row_ror rotate-accumulate (VALU pipe, no DS).
template <int CTRL>
__device__ __forceinline__ float ror_add(float x) {
    int y = __builtin_amdgcn_update_dpp(0, __float_as_int(x), CTRL, 0xF, 0xF, false);
    return x + __int_as_float(y);
}
__device__ __forceinline__ float red16(float x) {
    x = ror_add<0x121>(x);    // row_ror:1
    x = ror_add<0x122>(x);    // row_ror:2
    x = ror_add<0x124>(x);    // row_ror:4
    x = ror_add<0x128>(x);    // row_ror:8
    return x;
}

// Fast exact-GELU: erf via Abramowitz-Stegun 7.1.26 (|err| <= 1.5e-7)
__device__ __forceinline__ float fast_gelu(float x) {
    const float ax = fabsf(x) * 0.70710678118654752f;   // |x|/sqrt(2)
    const float t  = __builtin_amdgcn_rcpf(fmaf(0.3275911f, ax, 1.0f));
    float p = fmaf(1.061405429f, t, -1.453152027f);
    p = fmaf(p, t, 1.421413741f);
    p = fmaf(p, t, -0.284496736f);
    p = fmaf(p, t, 0.254829592f);
    p = p * t;
    const float e    = __expf(-ax * ax);
    const float erfa = fmaf(-p, e, 1.0f);               // erf(|x|/sqrt2)
    const float erfx = copysignf(erfa, x);
    return 0.5f * x * (1.0f + erfx);
}

// ---------------------------------------------------------------------------
// prep_conv (R10-proven flat map):
//  bid < 19200 : v_emb fp32 -> Av bf16, chunk-XOR-swizzled (key m&7, within
//                128B groups). Thread idx -> output chunk idx (linear stores,
//                coalesced permuted reads, NT loads).
//  bid < 19776 : W1 -> Wp bf16 [1536][768] transposed, same swizzle (key n&7)
//  bid == 19776: gw = gamma*W2
//  bid == 19777: scal = {sum gamma*W2, sum beta*W2 + b2}
// ---------------------------------------------------------------------------
__global__ __launch_bounds__(256) void prep_conv(
    const float* __restrict__ v, const float* __restrict__ W1,
    const float* __restrict__ gamma, const float* __restrict__ beta,
    const float* __restrict__ W2, const float* __restrict__ b2,
    bf16* __restrict__ Av, bf16* __restrict__ Wp,
    float* __restrict__ gw, float* __restrict__ scal)
{
    const int bid = blockIdx.x;
    if (bid < 19200) {
        const int idx = bid * 256 + threadIdx.x;           // 0..4915199
        const int m_  = idx / 96;                          // row (magic-mul)
        const int p   = idx - m_ * 96;                     // stored pos 0..95
        const int g   = (p & ~7) | ((p & 7) ^ (m_ & 7));   // content chunk
        const float* src = v + (size_t)m_ * HH + g * 8;
        f32x4v a = __builtin_nontemporal_load((const f32x4v*)src);
        f32x4v b = __builtin_nontemporal_load((const f32x4v*)(src + 4));
        bf16x8 o = { (bf16)a[0],(bf16)a[1],(bf16)a[2],(bf16)a[3],
                     (bf16)b[0],(bf16)b[1],(bf16)b[2],(bf16)b[3] };
        *(bf16x8*)(Av + (size_t)idx * 8) = o;
    } else if (bid < 19776) {
        // W1 transpose+convert+swizzle: thread -> one 16B output chunk
        const int t = (bid - 19200) * 256 + threadIdx.x;   // 0..147455
        const int n = t % II;                              // lane-consecutive
        const int g = t / II;                              // content chunk 0..95
        const int p = (g & ~7) | ((g & 7) ^ (n & 7));
        bf16x8 o;
        #pragma unroll
        for (int i = 0; i < 8; ++i)
            o[i] = (bf16)W1[(size_t)(g * 8 + i) * II + n]; // coalesced reads
        *(bf16x8*)&Wp[(size_t)n * HH + p * 8] = o;
    } else if (bid == 19776) {
        for (int j = threadIdx.x; j < II; j += 256)
            gw[j] = gamma[j] * W2[j];
    } else {
        float s1 = 0.f, s2 = 0.f;
        for (int j = threadIdx.x; j < II; j += 256) {
            float w2 = W2[j];
            s1 += gamma[j] * w2;
            s2 += beta[j]  * w2;
        }
        #pragma unroll
        for (int off = 32; off; off >>= 1) {
            s1 += __shfl_down(s1, off, 64);
            s2 += __shfl_down(s2, off, 64);
        }
        __shared__ float a1[4], a2[4];
        int lane = threadIdx.x & 63, w = threadIdx.x >> 6;
        if (lane == 0) { a1[w] = s1; a2[w] = s2; }
        __syncthreads();
        if (threadIdx.x == 0) {
            scal[0] = a1[0] + a1[1] + a1[2] + a1[3];
            scal[1] = a2[0] + a2[1] + a2[2] + a2[3] + b2[0];
        }
    }
}

// ---------------------------------------------------------------------------
// gemm_part: 512 threads / 8 waves, tile 128x256, BK=64, wave-tile 64x64
// (acc[4][4], 64 AGPR -- the R7-proven per-wave shape). Same proven sync
// (stage -> vmcnt(0)+__syncthreads -> 2 kb-phases -> __syncthreads), same
// baked XOR swizzle (row&7 == m15&7 for all reads). vs R10: BN=256 halves
// A-staging traffic (nb=6 not 12) and per-step gld_lds (6/thread not 8);
// LDS 54 KB -> 2 blocks/CU x 8 waves = 16 waves/CU (occupancy up).
// Grid 2400 = 8 XCDs x 300 = 400 mb x 6 nb.
// Epilogue: +b1, fast GELU, DPP row-reduce partials -> sred[4 wn][128][3]
// -> part[s][nb][row].
// ---------------------------------------------------------------------------
__global__ __launch_bounds__(512) void gemm_part(
    const bf16* __restrict__ Av, const bf16* __restrict__ Wp,
    const float* __restrict__ b1, const float* __restrict__ gw,
    float* __restrict__ part)
{
    __shared__ bf16  As[128 * 64];      // 16 KB
    __shared__ bf16  Bs[256 * 64];      // 32 KB
    __shared__ float sred[4][128][3];   // 6 KB

    const int tid  = threadIdx.x;
    // 2400 blocks = 8 XCDs x 300; 300 = 50 mb-groups x 6 nb
    const int lin  = (blockIdx.x & 7) * 300 + (blockIdx.x >> 3);
    const int mb   = lin / 6;
    const int nb   = lin % 6;
    const int lane = tid & 63;
    const int w    = tid >> 6;          // 0..7
    const int wm   = w >> 2;            // 0..1  (m half)
    const int wn   = w & 3;             // 0..3  (n quarter)
    const int m15  = lane & 15;
    const int q    = lane >> 4;         // 0..3
    const int row0 = mb * 128;

    // staging: thread t covers (row = i*64 + t/8, chunk pos = t&7), 16B each
    const int srow = tid >> 3;          // 0..63
    const int sc   = tid & 7;
    const bf16* aP = Av + (size_t)(row0     + srow) * HH + sc * 8;
    const bf16* bP = Wp + (size_t)(nb * 256 + srow) * HH + sc * 8;
    bf16* asD = As + tid * 8;           // call i adds i*4096 elems (8 KB)
    bf16* bsD = Bs + tid * 8;

    f32x4 acc[4][4] = {};

    for (int kt = 0; kt < 12; ++kt) {
        const int ko = kt * 64;
        // ---- stage K-tile kt (A: 2 calls, B: 4 calls; 64 rows each) ----
        #pragma unroll
        for (int i = 0; i < 2; ++i)
            gld_lds16(aP + (size_t)(64 * i) * HH + ko, asD + i * 4096);
        #pragma unroll
        for (int i = 0; i < 4; ++i)
            gld_lds16(bP + (size_t)(64 * i) * HH + ko, bsD + i * 4096);
        asm volatile("s_waitcnt vmcnt(0)" ::: "memory");
        __syncthreads();

        // ---- compute: 2 kb-phases over the 64-wide K-tile ----
        #pragma unroll
        for (int kb = 0; kb < 2; ++kb) {
            const int xsel = ((kb * 4 + q) ^ (m15 & 7)) * 8;
            bf16x8 af[4];
            #pragma unroll
            for (int mt = 0; mt < 4; ++mt)
                af[mt] = *(const bf16x8*)&As[(wm*64 + mt*16 + m15)*64 + xsel];
            #pragma unroll
            for (int nt = 0; nt < 4; ++nt) {
                bf16x8 bfr = *(const bf16x8*)&Bs[(wn*64 + nt*16 + m15)*64 + xsel];
                #pragma unroll
                for (int mt = 0; mt < 4; ++mt)
                    acc[mt][nt] = __builtin_amdgcn_mfma_f32_16x16x32_bf16(
                        af[mt], bfr, acc[mt][nt], 0, 0, 0);
            }
        }
        __syncthreads();
    }

    // ---- epilogue: +b1, fast GELU, per-row partial stats over 64 cols ----
    float bv[4], gv[4];
    #pragma unroll
    for (int nt = 0; nt < 4; ++nt) {
        const int col = nb*256 + wn*64 + nt*16 + m15;
        bv[nt] = b1[col];
        gv[nt] = gw[col];
    }

    #pragma unroll
    for (int mt = 0; mt < 4; ++mt) {
        #pragma unroll
        for (int r = 0; r < 4; ++r) {
            float x0 = 0.f, x1 = 0.f, x2 = 0.f;
            #pragma unroll
            for (int nt = 0; nt < 4; ++nt) {
                // C/D layout: col = lane&15, row = q*4 + r
                float g = fast_gelu(acc[mt][nt][r] + bv[nt]);
                x0 += g; x1 += g * g; x2 += g * gv[nt];
            }
            x0 = red16(x0); x1 = red16(x1); x2 = red16(x2);
            if (m15 == 0) {
                const int rl = wm*64 + mt*16 + q*4 + r;   // 0..127
                sred[wn][rl][0] = x0;
                sred[wn][rl][1] = x1;
                sred[wn][rl][2] = x2;
            }
        }
    }
    __syncthreads();

    if (tid < 128) {
        const size_t rg = (size_t)row0 + tid;
        #pragma unroll
        for (int s = 0; s < 3; ++s)
            part[(size_t)s * 6 * MM + (size_t)nb * MM + rg]
                = sred[0][tid][s] + sred[1][tid][s]
                + sred[2][tid][s] + sred[3][tid][s];
    }
}

// ---------------------------------------------------------------------------
// score_pred: finish LN + sigmoid for the 100 rows of batch b, write scores,
// then pred = sum(scores), logits = one_hot(clamp(round(pred),0,15))
// ---------------------------------------------------------------------------
__global__ __launch_bounds__(128) void score_pred(
    const float* __restrict__ part, const float* __restrict__ scal,
    float* __restrict__ o_scores, float* __restrict__ o_pred,
    float* __restrict__ o_logits)
{
    const int b = blockIdx.x, t = threadIdx.x;
    float s = 0.f;
    if (t < NN) {
        const size_t row = (size_t)b * NN + t;
        float Sh = 0.f, Shh = 0.f, Shg = 0.f;
        #pragma unroll
        for (int j = 0; j < 6; ++j) {
            Sh  += part[(size_t)0*6*MM + (size_t)j*MM + row];
            Shh += part[(size_t)1*6*MM + (size_t)j*MM + row];
            Shg += part[(size_t)2*6*MM + (size_t)j*MM + row];
        }
        const float mu   = Sh * (1.0f / II);
        const float var  = Shh * (1.0f / II) - mu * mu;
        const float rstd = rsqrtf(var + 1e-5f);
        const float z    = rstd * (Shg - mu * scal[0]) + scal[1];
        s = 1.0f / (1.0f + __expf(-z));
        o_scores[row] = s;
    }
    float v = s;
    #pragma unroll
    for (int off = 32; off; off >>= 1) v += __shfl_down(v, off, 64);
    __shared__ float ssum[2];
    const int lane = t & 63, w = t >> 6;
    if (lane == 0) ssum[w] = v;
    __syncthreads();
    const float p = ssum[0] + ssum[1];
    if (t == 0) o_pred[b] = p;
    if (t < 16) {
        int aid = (int)rintf(p);
        aid = aid < 0 ? 0 : (aid > 15 ? 15 : aid);
        o_logits[b * 16 + t] = (t == aid) ? 1.0f : 0.0f;
    }
}

// ---------------------------------------------------------------------------
extern "C" void kernel_launch(void* const* d_in, const int* in_sizes, int n_in,
                              void* d_out, int out_size, void* d_ws, size_t ws_size,
                              hipStream_t stream)
{
    const float* v_emb = (const float*)d_in[0];
    const float* W1    = (const float*)d_in[1];
    const float* b1    = (const float*)d_in[2];
    const float* gamma = (const float*)d_in[3];
    const float* beta  = (const float*)d_in[4];
    const float* W2    = (const float*)d_in[5];
    const float* b2    = (const float*)d_in[6];

    char* ws = (char*)d_ws;
    size_t off = 0;
    bf16*  Wp   = (bf16*)(ws + off);  off += (size_t)II * HH * 2;      // 2.36 MB
    float* gw   = (float*)(ws + off); off += (size_t)II * 4;
    float* scal = (float*)(ws + off); off += 256;
    float* part = (float*)(ws + off); off += (size_t)MM * 18 * 4;      // 3.69 MB
    bf16*  Av   = (bf16*)(ws + off);  off += (size_t)MM * HH * 2;      // 78.6 MB

    float* out       = (float*)d_out;
    float* o_scores  = out;            // 51200
    float* o_pred    = out + MM;       // 512
    float* o_logits  = out + MM + BB;  // 8192

    hipLaunchKernelGGL(prep_conv, dim3(19778), dim3(256), 0, stream,
                       v_emb, W1, gamma, beta, W2, b2, Av, Wp, gw, scal);
    hipLaunchKernelGGL(gemm_part, dim3((MM / 128) * 6), dim3(512),
                       0, stream, Av, Wp, b1, gw, part);
    hipLaunchKernelGGL(score_pred, dim3(BB), dim3(128), 0, stream,
                       part, scal, o_scores, o_pred, o_logits);
}